// Round 10
// baseline (203.876 us; speedup 1.0000x reference)
//
#include <hip/hip_runtime.h>
#include <hip/hip_bf16.h>

#define L_SEQ 512
#define D_EMB 256
#define NH 8
#define HD 32
#define LL (L_SEQ * L_SEQ)   // 262144

typedef __attribute__((ext_vector_type(8))) short short8;
typedef __attribute__((ext_vector_type(4))) float f32x4;
typedef unsigned short ushort;

__device__ __forceinline__ float bf2f(ushort u) {
    unsigned int x = ((unsigned int)u) << 16;
    float f;
    __builtin_memcpy(&f, &x, 4);
    return f;
}
__device__ __forceinline__ ushort f2bf(float x) {   // RNE (host-quality), prep only
    __hip_bfloat16 h = __float2bfloat16(x);
    ushort u;
    __builtin_memcpy(&u, &h, 2);
    return u;
}
__device__ __forceinline__ unsigned int fbits(float x) {
    unsigned int u;
    __builtin_memcpy(&u, &x, 4);
    return u;
}
__device__ __forceinline__ float asf(unsigned int u) {
    float f;
    __builtin_memcpy(&f, &u, 4);
    return f;
}
// pack bf16(a) | bf16(b)<<16, RNE, single VALU op (T12: no builtin on gfx950)
__device__ __forceinline__ unsigned int cvt_pk_bf16(float a, float b) {
    unsigned int r;
    asm("v_cvt_pk_bf16_f32 %0, %1, %2" : "=v"(r) : "v"(a), "v"(b));
    return r;
}
// hi16(x) | hi16(y)<<16  (one v_perm)
__device__ __forceinline__ unsigned int packhi(unsigned int y, unsigned int x) {
    return __builtin_amdgcn_perm(y, x, 0x07060302u);
}
// hi/lo split of two floats: .x = packed hi pair, .y = packed lo pair
__device__ __forceinline__ uint2 cvt_hilo2(float v0, float v1) {
    unsigned int hi = cvt_pk_bf16(v0, v1);
    float h0 = asf(hi << 16);
    float h1 = asf(hi & 0xffff0000u);
    unsigned int lo = cvt_pk_bf16(v0 - h0, v1 - h1);
    uint2 r; r.x = hi; r.y = lo;
    return r;
}

// ---------------------------------------------------------------------------
// prep: block 0 = tail reduction; block 1 = W1G table; block 2 = B2G table;
// blocks 3..258 = projection-weight transpose+hi/lo-split.
// ---------------------------------------------------------------------------
__global__ __launch_bounds__(256) void prep_kernel(
    const float* __restrict__ We1, const float* __restrict__ be1,
    const float* __restrict__ g,   const float* __restrict__ bta,
    const float* __restrict__ We2, const float* __restrict__ be2,
    const float* __restrict__ Wq, const float* __restrict__ Wk,
    const float* __restrict__ Wv, const float* __restrict__ Wp,
    ushort* __restrict__ W1G, ushort* __restrict__ B2G, float* __restrict__ tail,
    ushort* __restrict__ WThi, ushort* __restrict__ WTlo)
{
    int t = threadIdx.x;  // 0..255
    int bid = blockIdx.x;
    if (bid >= 3) {
        int bx = bid - 3;                 // 0..255
        int w = bx >> 6, ny = bx & 63;
        const float* W = (w == 0) ? Wq : (w == 1) ? Wk : (w == 2) ? Wv : Wp;
        ushort* dh = WThi + (size_t)w * 65536;
        ushort* dl = WTlo + (size_t)w * 65536;
        int n = ny * 4 + (t >> 6);
        int k0 = (t & 63) * 4;
        ushort hbuf[4], lbuf[4];
#pragma unroll
        for (int kk = 0; kk < 4; ++kk) {
            float v = W[(size_t)(k0 + kk) * 256 + n];
            unsigned int hb = fbits(v) + 0x8000u;
            ushort hi = (ushort)(hb >> 16);
            float res = v - bf2f(hi);
            hbuf[kk] = hi;
            lbuf[kk] = (ushort)((fbits(res) + 0x8000u) >> 16);
        }
        *(uint2*)(dh + (size_t)n * 256 + k0) = *(uint2*)&hbuf[0];
        *(uint2*)(dl + (size_t)n * 256 + k0) = *(uint2*)&lbuf[0];
        return;
    }

    if (bid == 1) {
        // first-layer weight table (permuted d, hi/lo rows)
        for (int idx = t; idx < 8192; idx += 256) {
            int j = idx & 7, lane = (idx >> 3) & 63, tile = idx >> 9;
            int m = lane & 15, q = lane >> 4;
            int k = q * 8 + j;
            int d = (m >> 2) * 64 + tile * 4 + (m & 3);   // permuted
            float v = 0.f;
            bool lo = false;
            if (k < 5)        v = We1[k * 256 + d];
            else if (k < 10)  { v = We1[(k - 5) * 256 + d]; lo = true; }
            else if (k < 15)  v = We1[(k - 10) * 256 + d];
            else if (k == 15) v = be1[d];
            else if (k == 16) { v = be1[d]; lo = true; }
            ushort hi = f2bf(v);
            W1G[idx] = lo ? f2bf(v - bf2f(hi)) : hi;
        }
        return;
    }
    if (bid == 2) {
        // Second-layer weight table.  k -> d map chosen so the first-layer
        // MFMA output registers ARE the second-layer A-fragment:
        // physical k = kc*32 + q*8 + s  <->  d = q*64 + kc*8 + s
        for (int idx = t; idx < 4096; idx += 256) {
            int j = idx & 7, lane = (idx >> 3) & 63, kc = idx >> 9;
            int n = lane & 15, q = lane >> 4;
            int d = q * 64 + kc * 8 + j;
            ushort out;
            if (n < 8)       out = f2bf(g[d] * We2[d * 8 + n]);
            else if (n == 8) out = 0x3F80;   // 1.0 bf16
            else             out = 0;
            B2G[idx] = out;
        }
        return;
    }

    // block 0: tail reduction
    __shared__ float red[16][256];
    float gd = g[t], bd = bta[t];
#pragma unroll
    for (int h = 0; h < 8; ++h) {
        float w2 = We2[t * 8 + h];
        red[h][t] = gd * w2;
        red[8 + h][t] = bd * w2;
    }
    __syncthreads();
    for (int off = 128; off > 0; off >>= 1) {
        if (t < off) {
#pragma unroll
            for (int row = 0; row < 16; ++row) red[row][t] += red[row][t + off];
        }
        __syncthreads();
    }
    if (t < 8) {
        tail[t] = red[t][0];
        tail[8 + t] = red[8 + t][0] + be2[t];
    }
    if (t >= 16 && t < 32) tail[t] = 0.f;
}

// ---------------------------------------------------------------------------
// gemm body: C[2048,256] = A @ W + bias (fp32-accurate via bf16 hi/lo).
// If Ct != null, write the (per b,h) transposed Kt layout instead.
// smem needs 10240 B: Ahi[64][40] | Alo[64][40].
// ---------------------------------------------------------------------------
__device__ __forceinline__ void gemm_body(
    const float* __restrict__ A, const ushort* __restrict__ BH,
    const ushort* __restrict__ BL, const float* __restrict__ bias,
    float* __restrict__ C, float* __restrict__ Ct,
    int bx, int by, char* smem)
{
    ushort* Ahi = (ushort*)smem;            // [64][40]
    ushort* Alo = (ushort*)(smem + 5120);   // [64][40]

    int tid = threadIdx.x;
    int wv = tid >> 6, lane = tid & 63;
    int m = lane & 15, quad = lane >> 4;
    int bm = bx * 64, bn = by * 64;

    int sm = tid >> 2, sg = (tid & 3) * 8;
    const float* Arow = A + (size_t)(bm + sm) * 256 + sg;

    int nrow = bn + wv * 16 + m;
    const ushort* bhp = BH + (size_t)nrow * 256 + quad * 8;
    const ushort* blp = BL + (size_t)nrow * 256 + quad * 8;

    f32x4 acc[4];
#pragma unroll
    for (int mt = 0; mt < 4; ++mt) acc[mt] = (f32x4){0.f, 0.f, 0.f, 0.f};

    for (int k0 = 0; k0 < 256; k0 += 32) {
        float4 a0 = *(const float4*)(Arow + k0);
        float4 a1 = *(const float4*)(Arow + k0 + 4);
        uint2 c0 = cvt_hilo2(a0.x, a0.y);
        uint2 c1 = cvt_hilo2(a0.z, a0.w);
        uint2 c2 = cvt_hilo2(a1.x, a1.y);
        uint2 c3 = cvt_hilo2(a1.z, a1.w);
        if (k0) __syncthreads();
        uint4 hq; hq.x = c0.x; hq.y = c1.x; hq.z = c2.x; hq.w = c3.x;
        uint4 lq; lq.x = c0.y; lq.y = c1.y; lq.z = c2.y; lq.w = c3.y;
        *(uint4*)&Ahi[sm * 40 + sg] = hq;
        *(uint4*)&Alo[sm * 40 + sg] = lq;
        __syncthreads();

        short8 bhi = *(const short8*)(bhp + k0);
        short8 blo = *(const short8*)(blp + k0);
#pragma unroll
        for (int mt = 0; mt < 4; ++mt) {
            short8 ahi = *(const short8*)&Ahi[(mt * 16 + m) * 40 + quad * 8];
            short8 alo = *(const short8*)&Alo[(mt * 16 + m) * 40 + quad * 8];
            acc[mt] = __builtin_amdgcn_mfma_f32_16x16x32_bf16(ahi, blo, acc[mt], 0, 0, 0);
            acc[mt] = __builtin_amdgcn_mfma_f32_16x16x32_bf16(alo, bhi, acc[mt], 0, 0, 0);
            acc[mt] = __builtin_amdgcn_mfma_f32_16x16x32_bf16(ahi, bhi, acc[mt], 0, 0, 0);
        }
    }

    float bn_bias = bias[nrow];
    if (Ct) {
        int bb = bm >> 9, l0 = bm & 511;
        float* outp = Ct + ((size_t)(bb * 256 + nrow)) * 512 + l0 + quad * 4;
#pragma unroll
        for (int mt = 0; mt < 4; ++mt) {
            float4 o;
            o.x = acc[mt][0] + bn_bias; o.y = acc[mt][1] + bn_bias;
            o.z = acc[mt][2] + bn_bias; o.w = acc[mt][3] + bn_bias;
            *(float4*)(outp + mt * 16) = o;
        }
    } else {
#pragma unroll
        for (int mt = 0; mt < 4; ++mt) {
#pragma unroll
            for (int r = 0; r < 4; ++r) {
                C[(size_t)(bm + mt * 16 + quad * 4 + r) * 256 + nrow] = acc[mt][r] + bn_bias;
            }
        }
    }
}

// ---------------------------------------------------------------------------
// gemm body, BM=32 variant for the standalone output projection: 256 blocks
// -> full CU coverage, half the serial per-block chain.
// smem needs 5120 B: Ahi[32][40] | Alo[32][40].
// ---------------------------------------------------------------------------
__device__ __forceinline__ void gemm_body32(
    const float* __restrict__ A, const ushort* __restrict__ BH,
    const ushort* __restrict__ BL, const float* __restrict__ bias,
    float* __restrict__ C, int bx, int by, char* smem)
{
    ushort* Ahi = (ushort*)smem;            // [32][40]
    ushort* Alo = (ushort*)(smem + 2560);   // [32][40]

    int tid = threadIdx.x;
    int wv = tid >> 6, lane = tid & 63;
    int m = lane & 15, quad = lane >> 4;
    int bm = bx * 32, bn = by * 64;

    int sm = tid >> 3, sg = (tid & 7) * 4;
    const float* Arow = A + (size_t)(bm + sm) * 256 + sg;

    int nrow = bn + wv * 16 + m;
    const ushort* bhp = BH + (size_t)nrow * 256 + quad * 8;
    const ushort* blp = BL + (size_t)nrow * 256 + quad * 8;

    f32x4 acc[2];
    acc[0] = (f32x4){0.f, 0.f, 0.f, 0.f};
    acc[1] = (f32x4){0.f, 0.f, 0.f, 0.f};

    for (int k0 = 0; k0 < 256; k0 += 32) {
        float4 a0 = *(const float4*)(Arow + k0);
        uint2 c0 = cvt_hilo2(a0.x, a0.y);
        uint2 c1 = cvt_hilo2(a0.z, a0.w);
        if (k0) __syncthreads();
        uint2 hq; hq.x = c0.x; hq.y = c1.x;
        uint2 lq; lq.x = c0.y; lq.y = c1.y;
        *(uint2*)&Ahi[sm * 40 + sg] = hq;
        *(uint2*)&Alo[sm * 40 + sg] = lq;
        __syncthreads();

        short8 bhi = *(const short8*)(bhp + k0);
        short8 blo = *(const short8*)(blp + k0);
#pragma unroll
        for (int mt = 0; mt < 2; ++mt) {
            short8 ahi = *(const short8*)&Ahi[(mt * 16 + m) * 40 + quad * 8];
            short8 alo = *(const short8*)&Alo[(mt * 16 + m) * 40 + quad * 8];
            acc[mt] = __builtin_amdgcn_mfma_f32_16x16x32_bf16(ahi, blo, acc[mt], 0, 0, 0);
            acc[mt] = __builtin_amdgcn_mfma_f32_16x16x32_bf16(alo, bhi, acc[mt], 0, 0, 0);
            acc[mt] = __builtin_amdgcn_mfma_f32_16x16x32_bf16(ahi, bhi, acc[mt], 0, 0, 0);
        }
    }

    float bn_bias = bias[nrow];
#pragma unroll
    for (int mt = 0; mt < 2; ++mt) {
#pragma unroll
        for (int r = 0; r < 4; ++r) {
            C[(size_t)(bm + mt * 16 + quad * 4 + r) * 256 + nrow] = acc[mt][r] + bn_bias;
        }
    }
}

// ---------------------------------------------------------------------------
// edge helpers
// ---------------------------------------------------------------------------
__device__ __forceinline__ short8 make_ef8(const float4& evA, float evB, int q) {
    unsigned int hb0 = fbits(evA.x), hb1 = fbits(evA.y), hb2 = fbits(evA.z),
                 hb3 = fbits(evA.w), hb4 = fbits(evB);
    float e0 = evA.x - asf(hb0 & 0xffff0000u);
    float e1 = evA.y - asf(hb1 & 0xffff0000u);
    float e2 = evA.z - asf(hb2 & 0xffff0000u);
    float e3 = evA.w - asf(hb3 & 0xffff0000u);
    float e4 = evB   - asf(hb4 & 0xffff0000u);
    unsigned int la0 = fbits(e0) + 0x8000u;
    unsigned int la1 = fbits(e1) + 0x8000u;
    unsigned int la2 = fbits(e2) + 0x8000u;
    unsigned int la3 = fbits(e3) + 0x8000u;
    unsigned int la4 = fbits(e4) + 0x8000u;
    unsigned int A0v = packhi(hb1, hb0);
    unsigned int A1v = packhi(hb3, hb2);
    unsigned int A2v = packhi(hb0, hb4);
    unsigned int A3v = packhi(hb2, hb1);
    unsigned int B0v = packhi(hb4, hb3);
    unsigned int B1v = packhi(la1, la0);
    unsigned int B2v = packhi(la3, la2);
    unsigned int B3v = packhi(0x3F800000u, la4);
    uint4 efd;
    bool isq0 = (q == 0), isq1 = (q == 1), isq2 = (q == 2);
    efd.x = isq0 ? A0v : isq1 ? B0v : isq2 ? 0x3F80u : 0u;
    efd.y = isq0 ? A1v : isq1 ? B1v : 0u;
    efd.z = isq0 ? A2v : isq1 ? B2v : 0u;
    efd.w = isq0 ? A3v : isq1 ? B3v : 0u;
    short8 ef8;
    __builtin_memcpy(&ef8, &efd, 16);
    return ef8;
}

__device__ __forceinline__ void ln_store(
    const f32x4& acc, const f32x4& acc2, float shv, float bbv,
    int lane, int n, int q, ushort* __restrict__ E2,
    int b, int i, int jb)
{
    const float inv256 = 1.0f / 256.0f;
    int base = lane & 48;
    float er[4];
#pragma unroll
    for (int r = 0; r < 4; ++r) {
        float sm = __shfl(acc[r], base + 8);
        float sq = __shfl(acc2[r], base + (base >> 2) + r);
        float dot = acc[r];
        float mu = sm * inv256;
        float var = fmaf(-mu, mu, sq * inv256);
        float rs = rsqrtf(var + 1e-5f);
        er[r] = fmaf(dot - mu * shv, rs, bbv);
    }
    if (n < 8) {
        uint2 outv;
        outv.x = cvt_pk_bf16(er[0], er[1]);
        outv.y = cvt_pk_bf16(er[2], er[3]);
        size_t basep = (((size_t)(b * NH + n) * L_SEQ + i) * L_SEQ) + jb + q * 4;
        *(uint2*)(E2 + basep) = outv;
    }
}

// ---------------------------------------------------------------------------
// edge body, 4 rows per block: amortizes the 24 KB w1/b2 LDS staging over
// 4 rows and drops edge block count 2048 -> 512 (fused grid 896 blocks is
// fully co-resident at ~6 blocks/CU LDS limit -> no dispatch-wave tails).
// Flat 16-iteration loop: row = it>>2, col-chunk = it&3; the ev prefetch
// chain runs across row seams.  Register pressure identical to R9 (same
// ev + prefetch set, loop-carried).
// ---------------------------------------------------------------------------
__device__ __forceinline__ void edge_body(
    const float* __restrict__ EF, const ushort* __restrict__ W1G,
    const ushort* __restrict__ B2G, const float* __restrict__ tail,
    ushort* __restrict__ E2, int ebid, char* smem)
{
    int tid = threadIdx.x;
    // stage fragment tables into LDS: w1 16KB @0, b2 8KB @16384
    {
        const uint4* s1 = (const uint4*)W1G;
        uint4* d1 = (uint4*)smem;
#pragma unroll
        for (int k = 0; k < 4; ++k) d1[tid + k * 256] = s1[tid + k * 256];
        const uint4* s2 = (const uint4*)B2G;
        uint4* d2 = (uint4*)(smem + 16384);
#pragma unroll
        for (int k = 0; k < 2; ++k) d2[tid + k * 256] = s2[tid + k * 256];
    }
    int wv = tid >> 6, lane = tid & 63;
    int q = lane >> 4, n = lane & 15;

    int b = ebid >> 7;            // 128 row-groups per batch
    int i0 = (ebid & 127) * 4;    // first of 4 consecutive rows

    float shv = tail[n];
    float bbv = tail[8 + n];

    // efb: batch b, row i0, col 0 (5 feats per (i,j))
    const float* efb = EF + ((size_t)(b * L_SEQ + i0) * L_SEQ) * 5;
    int pair0 = wv * 32 + n;            // col group 0; group 1 = +16

    const float* p0 = efb + (size_t)pair0 * 5;
    float4 evA0 = *(const float4*)p0;        float evB0 = p0[4];
    float4 evA1 = *(const float4*)(p0 + 80); float evB1 = p0[84];

    __syncthreads();
    const short8* w1l = (const short8*)smem;            // [16*64] frags
    const short8* b2l = (const short8*)(smem + 16384);  // [8*64] frags

    const f32x4 z = {0.f, 0.f, 0.f, 0.f};

    for (int it = 0; it < 16; ++it) {
        float4 nA0, nA1; float nB0 = 0.f, nB1 = 0.f;
        if (it < 15) {
            int nit = it + 1;
            const float* pn = efb + (size_t)(nit >> 2) * (L_SEQ * 5)
                                  + (size_t)((nit & 3) * 128 + pair0) * 5;
            nA0 = *(const float4*)pn;        nB0 = pn[4];
            nA1 = *(const float4*)(pn + 80); nB1 = pn[84];
        }
        int i  = i0 + (it >> 2);
        int jb0 = (it & 3) * 128 + wv * 32;

        short8 ef0 = make_ef8(evA0, evB0, q);
        short8 ef1 = make_ef8(evA1, evB1, q);

        f32x4 acc0 = z, acc20 = z, acc1 = z, acc21 = z;
#pragma unroll
        for (int kc = 0; kc < 8; ++kc) {
            short8 wa = w1l[2 * kc * 64 + lane];
            short8 wb = w1l[(2 * kc + 1) * 64 + lane];
            short8 b2 = b2l[kc * 64 + lane];
            f32x4 dA0 = __builtin_amdgcn_mfma_f32_16x16x32_bf16(wa, ef0, z, 0, 0, 0);
            f32x4 dB0 = __builtin_amdgcn_mfma_f32_16x16x32_bf16(wb, ef0, z, 0, 0, 0);
            f32x4 dA1 = __builtin_amdgcn_mfma_f32_16x16x32_bf16(wa, ef1, z, 0, 0, 0);
            f32x4 dB1 = __builtin_amdgcn_mfma_f32_16x16x32_bf16(wb, ef1, z, 0, 0, 0);
            uint4 av0, av1;
            av0.x = cvt_pk_bf16(fmaxf(dA0[0], 0.f), fmaxf(dA0[1], 0.f));
            av0.y = cvt_pk_bf16(fmaxf(dA0[2], 0.f), fmaxf(dA0[3], 0.f));
            av0.z = cvt_pk_bf16(fmaxf(dB0[0], 0.f), fmaxf(dB0[1], 0.f));
            av0.w = cvt_pk_bf16(fmaxf(dB0[2], 0.f), fmaxf(dB0[3], 0.f));
            av1.x = cvt_pk_bf16(fmaxf(dA1[0], 0.f), fmaxf(dA1[1], 0.f));
            av1.y = cvt_pk_bf16(fmaxf(dA1[2], 0.f), fmaxf(dA1[3], 0.f));
            av1.z = cvt_pk_bf16(fmaxf(dB1[0], 0.f), fmaxf(dB1[1], 0.f));
            av1.w = cvt_pk_bf16(fmaxf(dB1[2], 0.f), fmaxf(dB1[3], 0.f));
            short8 a0, a1;
            __builtin_memcpy(&a0, &av0, 16);
            __builtin_memcpy(&a1, &av1, 16);
            acc0  = __builtin_amdgcn_mfma_f32_16x16x32_bf16(a0, b2, acc0, 0, 0, 0);
            acc20 = __builtin_amdgcn_mfma_f32_16x16x32_bf16(a0, a0, acc20, 0, 0, 0);
            acc1  = __builtin_amdgcn_mfma_f32_16x16x32_bf16(a1, b2, acc1, 0, 0, 0);
            acc21 = __builtin_amdgcn_mfma_f32_16x16x32_bf16(a1, a1, acc21, 0, 0, 0);
        }

        ln_store(acc0, acc20, shv, bbv, lane, n, q, E2, b, i, jb0);
        ln_store(acc1, acc21, shv, bbv, lane, n, q, E2, b, i, jb0 + 16);

        evA0 = nA0; evB0 = nB0;
        evA1 = nA1; evB1 = nB1;
    }
}

// ---------------------------------------------------------------------------
// fused_qkv_edge: blocks 0..383 = QKV gemms (independent MFMA-heavy work),
// blocks 384..895 = edge row-groups (4 rows each).  896 blocks total ->
// whole grid co-resident.  launch_bounds(256,4): cap 128 VGPR.
// ---------------------------------------------------------------------------
__global__ __launch_bounds__(256, 4) void fused_qkv_edge(
    const float* __restrict__ query, const float* __restrict__ key,
    const float* __restrict__ value,
    const ushort* __restrict__ WThi, const ushort* __restrict__ WTlo,
    const float* __restrict__ bq, const float* __restrict__ bk,
    const float* __restrict__ bv,
    float* __restrict__ Qw, float* __restrict__ Ktw, float* __restrict__ Vw,
    const float* __restrict__ EF, const ushort* __restrict__ W1G,
    const ushort* __restrict__ B2G, const float* __restrict__ tail,
    ushort* __restrict__ E2)
{
    __shared__ __align__(16) char smem[24576];  // union: gemm 10240 / edge 24576
    int bid = blockIdx.x;
    if (bid < 384) {
        int z = bid >> 7, rem = bid & 127;
        int bx = rem & 31, by = rem >> 5;
        if (z == 0)
            gemm_body(query, WThi + 0 * 65536, WTlo + 0 * 65536, bq, Qw, nullptr, bx, by, smem);
        else if (z == 1)
            gemm_body(key,   WThi + 1 * 65536, WTlo + 1 * 65536, bk, nullptr, Ktw, bx, by, smem);
        else
            gemm_body(value, WThi + 2 * 65536, WTlo + 2 * 65536, bv, Vw, nullptr, bx, by, smem);
    } else {
        edge_body(EF, W1G, B2G, tail, E2, bid - 384, smem);
    }
}

// ---------------------------------------------------------------------------
// gemm_out: output projection, BM=32 -> grid (64,4) = 256 blocks.
// ---------------------------------------------------------------------------
__global__ __launch_bounds__(256) void gemm_out(
    const float* __restrict__ A, const ushort* __restrict__ BH,
    const ushort* __restrict__ BL, const float* __restrict__ bias,
    float* __restrict__ C)
{
    __shared__ __align__(16) char smem[5120];
    gemm_body32(A, BH, BL, bias, C, blockIdx.x, blockIdx.y, smem);
}

// ---------------------------------------------------------------------------
// attn (R1/R2-proven version, unchanged): single-buffer staged K/V with
// register staging, pbuf for the P transpose, 2 barriers per chunk.
// Best-measured attn across 10 rounds (<=49.9 us, no spills).
// pbuf is the deliberate cross-phase spill target for s[][] — do NOT
// replace it with registers/shuffle (R8: +35 MB scratch) or delete the
// staging (R3: +200 MB scratch).
// ---------------------------------------------------------------------------
__global__ __launch_bounds__(256, 4) void attn_kernel(
    const float* __restrict__ Q, const float* __restrict__ Kt,
    const float* __restrict__ V, const ushort* __restrict__ E2,
    const int* __restrict__ MSK, float* __restrict__ Y)
{
    __shared__ float stage[4096];         // 16 KB: K chunk [32][128] / V chunk [128][32]
    __shared__ ushort pbuf[4][512][4];    // 16 KB: [wave][j][row] bf16

    int bh = blockIdx.x;
    int b = bh >> 3, h = bh & 7;
    int tid = threadIdx.x;
    int wv = tid >> 6, lane = tid & 63;
    int i0 = blockIdx.y * 16;
    int i = i0 + wv * 4;

    const float* Ktb = Kt + (size_t)bh * (HD * L_SEQ);
    const float* Vb  = V + (size_t)b * L_SEQ * D_EMB + h * HD;

    int wvu = __builtin_amdgcn_readfirstlane(wv);
    const float* Qs = Q + ((size_t)(b * L_SEQ + i0 + wvu * 4)) * 256 + h * HD;

    size_t erow = ((size_t)bh * L_SEQ + i) * L_SEQ;
    size_t mrow = ((size_t)b * L_SEQ + i) * L_SEQ;

    unsigned int e2p[4][4];
    int2 mkp[4][4];
#pragma unroll
    for (int r = 0; r < 4; ++r)
#pragma unroll
        for (int c = 0; c < 4; ++c) {
            int j = c * 128 + 2 * lane;
            e2p[r][c] = *(const unsigned int*)(E2 + erow + (size_t)r * L_SEQ + j);
            mkp[r][c] = *(const int2*)(MSK + mrow + (size_t)r * L_SEQ + j);
        }

    float s[4][8];
#pragma unroll
    for (int r = 0; r < 4; ++r)
#pragma unroll
        for (int t = 0; t < 8; ++t) s[r][t] = 0.f;

    for (int c = 0; c < 4; ++c) {
        if (c) __syncthreads();
        {
            int d0 = tid >> 5, jj = (tid & 31) * 4;
#pragma unroll
            for (int p = 0; p < 4; ++p) {
                int d = p * 8 + d0;
                float4 kv = *(const float4*)(Ktb + (size_t)d * L_SEQ + c * 128 + jj);
                *(float4*)&stage[d * 128 + jj] = kv;
            }
        }
        __syncthreads();
        int c2 = c * 2;
#pragma unroll
        for (int d = 0; d < HD; ++d) {
            float q0 = Qs[0 * 256 + d];
            float q1 = Qs[1 * 256 + d];
            float q2 = Qs[2 * 256 + d];
            float q3 = Qs[3 * 256 + d];
            float2 kv = *(const float2*)&stage[d * 128 + 2 * lane];
            s[0][c2]     = fmaf(q0, kv.x, s[0][c2]);
            s[0][c2 + 1] = fmaf(q0, kv.y, s[0][c2 + 1]);
            s[1][c2]     = fmaf(q1, kv.x, s[1][c2]);
            s[1][c2 + 1] = fmaf(q1, kv.y, s[1][c2 + 1]);
            s[2][c2]     = fmaf(q2, kv.x, s[2][c2]);
            s[2][c2 + 1] = fmaf(q2, kv.y, s[2][c2 + 1]);
            s[3][c2]     = fmaf(q3, kv.x, s[3][c2]);
            s[3][c2 + 1] = fmaf(q3, kv.y, s[3][c2 + 1]);
        }
    }

    const float scl = 0.17677669529663687f;  // 1/sqrt(32)
#pragma unroll
    for (int r = 0; r < 4; ++r) {
        float m = -3.0e38f;
#pragma unroll
        for (int idx = 0; idx < 8; ++idx) {
            int c = idx >> 1, u = idx & 1;
            unsigned int pk = e2p[r][c];
            float e = bf2f((ushort)(u ? (pk >> 16) : (pk & 0xffff)));
            int mk = u ? mkp[r][c].y : mkp[r][c].x;
            float v = (mk != 0) ? fmaf(s[r][idx], scl, e) : -1e30f;
            s[r][idx] = v;
            m = fmaxf(m, v);
        }
#pragma unroll
        for (int o = 32; o > 0; o >>= 1) m = fmaxf(m, __shfl_xor(m, o));
        float ssum = 0.f;
#pragma unroll
        for (int idx = 0; idx < 8; ++idx) {
            float p = __expf(s[r][idx] - m);
            s[r][idx] = p;
            ssum += p;
        }
#pragma unroll
        for (int o = 32; o > 0; o >>= 1) ssum += __shfl_xor(ssum, o);
        float inv = 1.0f / ssum;
#pragma unroll
        for (int idx = 0; idx < 8; ++idx) s[r][idx] *= inv;
    }
#pragma unroll
    for (int c = 0; c < 4; ++c) {
        int c2 = c * 2;
        uint4 w;
        w.x = cvt_pk_bf16(s[0][c2],     s[1][c2]);
        w.y = cvt_pk_bf16(s[2][c2],     s[3][c2]);
        w.z = cvt_pk_bf16(s[0][c2 + 1], s[1][c2 + 1]);
        w.w = cvt_pk_bf16(s[2][c2 + 1], s[3][c2 + 1]);
        *(uint4*)&pbuf[wv][c * 128 + 2 * lane][0] = w;
    }

    int dg = lane >> 3, js = lane & 7;
    float4 acc[4];
#pragma unroll
    for (int r = 0; r < 4; ++r) { acc[r].x = 0.f; acc[r].y = 0.f; acc[r].z = 0.f; acc[r].w = 0.f; }

    for (int c = 0; c < 4; ++c) {
        __syncthreads();
        {
            int j0 = tid >> 3, dd = (tid & 7) * 4;
#pragma unroll
            for (int p = 0; p < 4; ++p) {
                int j = p * 32 + j0;
                float4 vv = *(const float4*)(Vb + (size_t)(c * 128 + j) * D_EMB + dd);
                *(float4*)&stage[j * 32 + dd] = vv;
            }
        }
        __syncthreads();
#pragma unroll
        for (int jb = 0; jb < 16; ++jb) {
            int jj = jb * 8 + js;
            float4 v4 = *(const float4*)&stage[jj * 32 + dg * 4];
            uint2 pu = *(const uint2*)&pbuf[wv][c * 128 + jj][0];
            float p0 = asf(pu.x << 16);
            float p1 = asf(pu.x & 0xffff0000u);
            float p2 = asf(pu.y << 16);
            float p3 = asf(pu.y & 0xffff0000u);
            acc[0].x = fmaf(p0, v4.x, acc[0].x);
            acc[0].y = fmaf(p0, v4.y, acc[0].y);
            acc[0].z = fmaf(p0, v4.z, acc[0].z);
            acc[0].w = fmaf(p0, v4.w, acc[0].w);
            acc[1].x = fmaf(p1, v4.x, acc[1].x);
            acc[1].y = fmaf(p1, v4.y, acc[1].y);
            acc[1].z = fmaf(p1, v4.z, acc[1].z);
            acc[1].w = fmaf(p1, v4.w, acc[1].w);
            acc[2].x = fmaf(p2, v4.x, acc[2].x);
            acc[2].y = fmaf(p2, v4.y, acc[2].y);
            acc[2].z = fmaf(p2, v4.z, acc[2].z);
            acc[2].w = fmaf(p2, v4.w, acc[2].w);
            acc[3].x = fmaf(p3, v4.x, acc[3].x);
            acc[3].y = fmaf(p3, v4.y, acc[3].y);
            acc[3].z = fmaf(p3, v4.z, acc[3].z);
            acc[3].w = fmaf(p3, v4.w, acc[3].w);
        }
    }

#pragma unroll
    for (int off = 1; off < 8; off <<= 1) {
#pragma unroll
        for (int r = 0; r < 4; ++r) {
            acc[r].x += __shfl_xor(acc[r].x, off);
            acc[r].y += __shfl_xor(acc[r].y, off);
            acc[r].z += __shfl_xor(acc[r].z, off);
            acc[r].w += __shfl_xor(acc[r].w, off);
        }
    }
    if (js == 0) {
#pragma unroll
        for (int r = 0; r < 4; ++r)
            *(float4*)(Y + ((size_t)(b * L_SEQ + i + r)) * 256 + h * HD + dg * 4) = acc[r];
    }
}

// ---------------------------------------------------------------------------
extern "C" void kernel_launch(void* const* d_in, const int* in_sizes, int n_in,
                              void* d_out, int out_size, void* d_ws, size_t ws_size,
                              hipStream_t stream)
{
    const float* key   = (const float*)d_in[0];
    const float* value = (const float*)d_in[1];
    const float* query = (const float*)d_in[2];
    const int*   msk   = (const int*)d_in[3];
    const float* ef    = (const float*)d_in[4];
    const float* Wk  = (const float*)d_in[5];  const float* bk  = (const float*)d_in[6];
    const float* Wq  = (const float*)d_in[7];  const float* bq  = (const float*)d_in[8];
    const float* Wv  = (const float*)d_in[9];  const float* bv  = (const float*)d_in[10];
    const float* Wp  = (const float*)d_in[11]; const float* bp  = (const float*)d_in[12];
    const float* We1 = (const float*)d_in[13]; const float* be1 = (const float*)d_in[14];
    const float* lng = (const float*)d_in[15]; const float* lnb = (const float*)d_in[16];
    const float* We2 = (const float*)d_in[17]; const float* be2 = (const float*)d_in[18];

    const int MTOK = 4 * L_SEQ;          // 2048 rows
    const int NELT = MTOK * D_EMB;       // 524288

    float* ws    = (float*)d_ws;
    float* Qw    = ws;
    float* Vw    = Qw + NELT;
    float* Yw    = Vw + NELT;
    float* Ktw   = Yw + NELT;
    ushort* W1G  = (ushort*)(Ktw + NELT);   // 8192 bf16
    ushort* B2G  = W1G + 8192;              // 4096 bf16
    float* tail  = (float*)(B2G + 4096);    // 32 floats
    ushort* WThi = (ushort*)(tail + 32);    // 4*65536 bf16 (512 KB)
    ushort* WTlo = WThi + 4 * 65536;        // 4*65536 bf16 (512 KB)
    ushort* E2   = WTlo + 4 * 65536;        // 8388608 bf16 (~16.8 MB)

    hipLaunchKernelGGL(prep_kernel, dim3(259), dim3(256), 0, stream,
                       We1, be1, lng, lnb, We2, be2,
                       Wq, Wk, Wv, Wp,
                       W1G, B2G, tail, WThi, WTlo);
    hipLaunchKernelGGL(fused_qkv_edge, dim3(896), dim3(256), 0, stream,
                       query, key, value, WThi, WTlo, bq, bk, bv,
                       Qw, Ktw, Vw,
                       ef, W1G, B2G, tail, E2);
    hipLaunchKernelGGL(attn_kernel, dim3(32, 32), dim3(256), 0, stream,
                       Qw, Ktw, Vw, E2, msk, Yw);
    hipLaunchKernelGGL(gemm_out, dim3(64, 4), dim3(256), 0, stream,
                       Yw, WThi + 3 * 65536, WTlo + 3 * 65536, bp, (float*)d_out);
}

// Round 12
// 196.067 us; speedup vs baseline: 1.0398x; 1.0398x over previous
//
#include <hip/hip_runtime.h>
#include <hip/hip_bf16.h>

#define L_SEQ 512
#define D_EMB 256
#define NH 8
#define HD 32
#define LL (L_SEQ * L_SEQ)   // 262144

typedef __attribute__((ext_vector_type(8))) short short8;
typedef __attribute__((ext_vector_type(4))) float f32x4;
typedef unsigned short ushort;

__device__ __forceinline__ float bf2f(ushort u) {
    unsigned int x = ((unsigned int)u) << 16;
    float f;
    __builtin_memcpy(&f, &x, 4);
    return f;
}
__device__ __forceinline__ ushort f2bf(float x) {   // RNE (host-quality), prep only
    __hip_bfloat16 h = __float2bfloat16(x);
    ushort u;
    __builtin_memcpy(&u, &h, 2);
    return u;
}
__device__ __forceinline__ unsigned int fbits(float x) {
    unsigned int u;
    __builtin_memcpy(&u, &x, 4);
    return u;
}
__device__ __forceinline__ float asf(unsigned int u) {
    float f;
    __builtin_memcpy(&f, &u, 4);
    return f;
}
// pack bf16(a) | bf16(b)<<16, RNE, single VALU op (T12: no builtin on gfx950)
__device__ __forceinline__ unsigned int cvt_pk_bf16(float a, float b) {
    unsigned int r;
    asm("v_cvt_pk_bf16_f32 %0, %1, %2" : "=v"(r) : "v"(a), "v"(b));
    return r;
}
// hi16(x) | hi16(y)<<16  (one v_perm)
__device__ __forceinline__ unsigned int packhi(unsigned int y, unsigned int x) {
    return __builtin_amdgcn_perm(y, x, 0x07060302u);
}
// hi/lo split of two floats: .x = packed hi pair, .y = packed lo pair
__device__ __forceinline__ uint2 cvt_hilo2(float v0, float v1) {
    unsigned int hi = cvt_pk_bf16(v0, v1);
    float h0 = asf(hi << 16);
    float h1 = asf(hi & 0xffff0000u);
    unsigned int lo = cvt_pk_bf16(v0 - h0, v1 - h1);
    uint2 r; r.x = hi; r.y = lo;
    return r;
}

// ---------------------------------------------------------------------------
// prep: block 0 = tail reduction; block 1 = W1G table; block 2 = B2G table;
// blocks 3..258 = projection-weight transpose+hi/lo-split.
// ---------------------------------------------------------------------------
__global__ __launch_bounds__(256) void prep_kernel(
    const float* __restrict__ We1, const float* __restrict__ be1,
    const float* __restrict__ g,   const float* __restrict__ bta,
    const float* __restrict__ We2, const float* __restrict__ be2,
    const float* __restrict__ Wq, const float* __restrict__ Wk,
    const float* __restrict__ Wv, const float* __restrict__ Wp,
    ushort* __restrict__ W1G, ushort* __restrict__ B2G, float* __restrict__ tail,
    ushort* __restrict__ WThi, ushort* __restrict__ WTlo)
{
    int t = threadIdx.x;  // 0..255
    int bid = blockIdx.x;
    if (bid >= 3) {
        int bx = bid - 3;                 // 0..255
        int w = bx >> 6, ny = bx & 63;
        const float* W = (w == 0) ? Wq : (w == 1) ? Wk : (w == 2) ? Wv : Wp;
        ushort* dh = WThi + (size_t)w * 65536;
        ushort* dl = WTlo + (size_t)w * 65536;
        int n = ny * 4 + (t >> 6);
        int k0 = (t & 63) * 4;
        ushort hbuf[4], lbuf[4];
#pragma unroll
        for (int kk = 0; kk < 4; ++kk) {
            float v = W[(size_t)(k0 + kk) * 256 + n];
            unsigned int hb = fbits(v) + 0x8000u;
            ushort hi = (ushort)(hb >> 16);
            float res = v - bf2f(hi);
            hbuf[kk] = hi;
            lbuf[kk] = (ushort)((fbits(res) + 0x8000u) >> 16);
        }
        *(uint2*)(dh + (size_t)n * 256 + k0) = *(uint2*)&hbuf[0];
        *(uint2*)(dl + (size_t)n * 256 + k0) = *(uint2*)&lbuf[0];
        return;
    }

    if (bid == 1) {
        // first-layer weight table (permuted d, hi/lo rows)
        for (int idx = t; idx < 8192; idx += 256) {
            int j = idx & 7, lane = (idx >> 3) & 63, tile = idx >> 9;
            int m = lane & 15, q = lane >> 4;
            int k = q * 8 + j;
            int d = (m >> 2) * 64 + tile * 4 + (m & 3);   // permuted
            float v = 0.f;
            bool lo = false;
            if (k < 5)        v = We1[k * 256 + d];
            else if (k < 10)  { v = We1[(k - 5) * 256 + d]; lo = true; }
            else if (k < 15)  v = We1[(k - 10) * 256 + d];
            else if (k == 15) v = be1[d];
            else if (k == 16) { v = be1[d]; lo = true; }
            ushort hi = f2bf(v);
            W1G[idx] = lo ? f2bf(v - bf2f(hi)) : hi;
        }
        return;
    }
    if (bid == 2) {
        // Second-layer weight table.  k -> d map chosen so the first-layer
        // MFMA output registers ARE the second-layer A-fragment:
        // physical k = kc*32 + q*8 + s  <->  d = q*64 + kc*8 + s
        for (int idx = t; idx < 4096; idx += 256) {
            int j = idx & 7, lane = (idx >> 3) & 63, kc = idx >> 9;
            int n = lane & 15, q = lane >> 4;
            int d = q * 64 + kc * 8 + j;
            ushort out;
            if (n < 8)       out = f2bf(g[d] * We2[d * 8 + n]);
            else if (n == 8) out = 0x3F80;   // 1.0 bf16
            else             out = 0;
            B2G[idx] = out;
        }
        return;
    }

    // block 0: tail reduction
    __shared__ float red[16][256];
    float gd = g[t], bd = bta[t];
#pragma unroll
    for (int h = 0; h < 8; ++h) {
        float w2 = We2[t * 8 + h];
        red[h][t] = gd * w2;
        red[8 + h][t] = bd * w2;
    }
    __syncthreads();
    for (int off = 128; off > 0; off >>= 1) {
        if (t < off) {
#pragma unroll
            for (int row = 0; row < 16; ++row) red[row][t] += red[row][t + off];
        }
        __syncthreads();
    }
    if (t < 8) {
        tail[t] = red[t][0];
        tail[8 + t] = red[8 + t][0] + be2[t];
    }
    if (t >= 16 && t < 32) tail[t] = 0.f;
}

// ---------------------------------------------------------------------------
// gemm body: C[2048,256] = A @ W + bias (fp32-accurate via bf16 hi/lo).
// If Ct != null, write the (per b,h) transposed Kt layout instead.
// smem needs 10240 B: Ahi[64][40] | Alo[64][40].
// ---------------------------------------------------------------------------
__device__ __forceinline__ void gemm_body(
    const float* __restrict__ A, const ushort* __restrict__ BH,
    const ushort* __restrict__ BL, const float* __restrict__ bias,
    float* __restrict__ C, float* __restrict__ Ct,
    int bx, int by, char* smem)
{
    ushort* Ahi = (ushort*)smem;            // [64][40]
    ushort* Alo = (ushort*)(smem + 5120);   // [64][40]

    int tid = threadIdx.x;
    int wv = tid >> 6, lane = tid & 63;
    int m = lane & 15, quad = lane >> 4;
    int bm = bx * 64, bn = by * 64;

    int sm = tid >> 2, sg = (tid & 3) * 8;
    const float* Arow = A + (size_t)(bm + sm) * 256 + sg;

    int nrow = bn + wv * 16 + m;
    const ushort* bhp = BH + (size_t)nrow * 256 + quad * 8;
    const ushort* blp = BL + (size_t)nrow * 256 + quad * 8;

    f32x4 acc[4];
#pragma unroll
    for (int mt = 0; mt < 4; ++mt) acc[mt] = (f32x4){0.f, 0.f, 0.f, 0.f};

    for (int k0 = 0; k0 < 256; k0 += 32) {
        float4 a0 = *(const float4*)(Arow + k0);
        float4 a1 = *(const float4*)(Arow + k0 + 4);
        uint2 c0 = cvt_hilo2(a0.x, a0.y);
        uint2 c1 = cvt_hilo2(a0.z, a0.w);
        uint2 c2 = cvt_hilo2(a1.x, a1.y);
        uint2 c3 = cvt_hilo2(a1.z, a1.w);
        if (k0) __syncthreads();
        uint4 hq; hq.x = c0.x; hq.y = c1.x; hq.z = c2.x; hq.w = c3.x;
        uint4 lq; lq.x = c0.y; lq.y = c1.y; lq.z = c2.y; lq.w = c3.y;
        *(uint4*)&Ahi[sm * 40 + sg] = hq;
        *(uint4*)&Alo[sm * 40 + sg] = lq;
        __syncthreads();

        short8 bhi = *(const short8*)(bhp + k0);
        short8 blo = *(const short8*)(blp + k0);
#pragma unroll
        for (int mt = 0; mt < 4; ++mt) {
            short8 ahi = *(const short8*)&Ahi[(mt * 16 + m) * 40 + quad * 8];
            short8 alo = *(const short8*)&Alo[(mt * 16 + m) * 40 + quad * 8];
            acc[mt] = __builtin_amdgcn_mfma_f32_16x16x32_bf16(ahi, blo, acc[mt], 0, 0, 0);
            acc[mt] = __builtin_amdgcn_mfma_f32_16x16x32_bf16(alo, bhi, acc[mt], 0, 0, 0);
            acc[mt] = __builtin_amdgcn_mfma_f32_16x16x32_bf16(ahi, bhi, acc[mt], 0, 0, 0);
        }
    }

    float bn_bias = bias[nrow];
    if (Ct) {
        int bb = bm >> 9, l0 = bm & 511;
        float* outp = Ct + ((size_t)(bb * 256 + nrow)) * 512 + l0 + quad * 4;
#pragma unroll
        for (int mt = 0; mt < 4; ++mt) {
            float4 o;
            o.x = acc[mt][0] + bn_bias; o.y = acc[mt][1] + bn_bias;
            o.z = acc[mt][2] + bn_bias; o.w = acc[mt][3] + bn_bias;
            *(float4*)(outp + mt * 16) = o;
        }
    } else {
#pragma unroll
        for (int mt = 0; mt < 4; ++mt) {
#pragma unroll
            for (int r = 0; r < 4; ++r) {
                C[(size_t)(bm + mt * 16 + quad * 4 + r) * 256 + nrow] = acc[mt][r] + bn_bias;
            }
        }
    }
}

// ---------------------------------------------------------------------------
// gemm body, BM=32 variant for the standalone output projection: grid must
// be (64, 4) = 256 blocks (bm = bx*32 covers 2048 rows only with bx<64 —
// the R11 failure was launching this with 32 x-blocks).
// smem needs 5120 B: Ahi[32][40] | Alo[32][40].
// ---------------------------------------------------------------------------
__device__ __forceinline__ void gemm_body32(
    const float* __restrict__ A, const ushort* __restrict__ BH,
    const ushort* __restrict__ BL, const float* __restrict__ bias,
    float* __restrict__ C, int bx, int by, char* smem)
{
    ushort* Ahi = (ushort*)smem;            // [32][40]
    ushort* Alo = (ushort*)(smem + 2560);   // [32][40]

    int tid = threadIdx.x;
    int wv = tid >> 6, lane = tid & 63;
    int m = lane & 15, quad = lane >> 4;
    int bm = bx * 32, bn = by * 64;

    int sm = tid >> 3, sg = (tid & 7) * 4;
    const float* Arow = A + (size_t)(bm + sm) * 256 + sg;

    int nrow = bn + wv * 16 + m;
    const ushort* bhp = BH + (size_t)nrow * 256 + quad * 8;
    const ushort* blp = BL + (size_t)nrow * 256 + quad * 8;

    f32x4 acc[2];
    acc[0] = (f32x4){0.f, 0.f, 0.f, 0.f};
    acc[1] = (f32x4){0.f, 0.f, 0.f, 0.f};

    for (int k0 = 0; k0 < 256; k0 += 32) {
        float4 a0 = *(const float4*)(Arow + k0);
        uint2 c0 = cvt_hilo2(a0.x, a0.y);
        uint2 c1 = cvt_hilo2(a0.z, a0.w);
        if (k0) __syncthreads();
        uint2 hq; hq.x = c0.x; hq.y = c1.x;
        uint2 lq; lq.x = c0.y; lq.y = c1.y;
        *(uint2*)&Ahi[sm * 40 + sg] = hq;
        *(uint2*)&Alo[sm * 40 + sg] = lq;
        __syncthreads();

        short8 bhi = *(const short8*)(bhp + k0);
        short8 blo = *(const short8*)(blp + k0);
#pragma unroll
        for (int mt = 0; mt < 2; ++mt) {
            short8 ahi = *(const short8*)&Ahi[(mt * 16 + m) * 40 + quad * 8];
            short8 alo = *(const short8*)&Alo[(mt * 16 + m) * 40 + quad * 8];
            acc[mt] = __builtin_amdgcn_mfma_f32_16x16x32_bf16(ahi, blo, acc[mt], 0, 0, 0);
            acc[mt] = __builtin_amdgcn_mfma_f32_16x16x32_bf16(alo, bhi, acc[mt], 0, 0, 0);
            acc[mt] = __builtin_amdgcn_mfma_f32_16x16x32_bf16(ahi, bhi, acc[mt], 0, 0, 0);
        }
    }

    float bn_bias = bias[nrow];
#pragma unroll
    for (int mt = 0; mt < 2; ++mt) {
#pragma unroll
        for (int r = 0; r < 4; ++r) {
            C[(size_t)(bm + mt * 16 + quad * 4 + r) * 256 + nrow] = acc[mt][r] + bn_bias;
        }
    }
}

// ---------------------------------------------------------------------------
// edge helpers
// ---------------------------------------------------------------------------
__device__ __forceinline__ short8 make_ef8(const float4& evA, float evB, int q) {
    unsigned int hb0 = fbits(evA.x), hb1 = fbits(evA.y), hb2 = fbits(evA.z),
                 hb3 = fbits(evA.w), hb4 = fbits(evB);
    float e0 = evA.x - asf(hb0 & 0xffff0000u);
    float e1 = evA.y - asf(hb1 & 0xffff0000u);
    float e2 = evA.z - asf(hb2 & 0xffff0000u);
    float e3 = evA.w - asf(hb3 & 0xffff0000u);
    float e4 = evB   - asf(hb4 & 0xffff0000u);
    unsigned int la0 = fbits(e0) + 0x8000u;
    unsigned int la1 = fbits(e1) + 0x8000u;
    unsigned int la2 = fbits(e2) + 0x8000u;
    unsigned int la3 = fbits(e3) + 0x8000u;
    unsigned int la4 = fbits(e4) + 0x8000u;
    unsigned int A0v = packhi(hb1, hb0);
    unsigned int A1v = packhi(hb3, hb2);
    unsigned int A2v = packhi(hb0, hb4);
    unsigned int A3v = packhi(hb2, hb1);
    unsigned int B0v = packhi(hb4, hb3);
    unsigned int B1v = packhi(la1, la0);
    unsigned int B2v = packhi(la3, la2);
    unsigned int B3v = packhi(0x3F800000u, la4);
    uint4 efd;
    bool isq0 = (q == 0), isq1 = (q == 1), isq2 = (q == 2);
    efd.x = isq0 ? A0v : isq1 ? B0v : isq2 ? 0x3F80u : 0u;
    efd.y = isq0 ? A1v : isq1 ? B1v : 0u;
    efd.z = isq0 ? A2v : isq1 ? B2v : 0u;
    efd.w = isq0 ? A3v : isq1 ? B3v : 0u;
    short8 ef8;
    __builtin_memcpy(&ef8, &efd, 16);
    return ef8;
}

__device__ __forceinline__ void ln_store(
    const f32x4& acc, const f32x4& acc2, float shv, float bbv,
    int lane, int n, int q, ushort* __restrict__ E2,
    int b, int i, int jb)
{
    const float inv256 = 1.0f / 256.0f;
    int base = lane & 48;
    float er[4];
#pragma unroll
    for (int r = 0; r < 4; ++r) {
        float sm = __shfl(acc[r], base + 8);
        float sq = __shfl(acc2[r], base + (base >> 2) + r);
        float dot = acc[r];
        float mu = sm * inv256;
        float var = fmaf(-mu, mu, sq * inv256);
        float rs = rsqrtf(var + 1e-5f);
        er[r] = fmaf(dot - mu * shv, rs, bbv);
    }
    if (n < 8) {
        uint2 outv;
        outv.x = cvt_pk_bf16(er[0], er[1]);
        outv.y = cvt_pk_bf16(er[2], er[3]);
        size_t basep = (((size_t)(b * NH + n) * L_SEQ + i) * L_SEQ) + jb + q * 4;
        *(uint2*)(E2 + basep) = outv;
    }
}

// ---------------------------------------------------------------------------
// edge body (R2-proven config): w1 (16 KB) AND b2 (8 KB) fragment tables in
// LDS, staged once per block.  32 j-columns per wave-iteration.
// 1 row per block — measured optimum (R10's 4-row amortization cut fused
// occupancy 36->19 and regressed +8 us; grid 2432 keeps CUs backfilled).
// ---------------------------------------------------------------------------
__device__ __forceinline__ void edge_body(
    const float* __restrict__ EF, const ushort* __restrict__ W1G,
    const ushort* __restrict__ B2G, const float* __restrict__ tail,
    ushort* __restrict__ E2, int bi, char* smem)
{
    int tid = threadIdx.x;
    // stage fragment tables into LDS: w1 16KB @0, b2 8KB @16384
    {
        const uint4* s1 = (const uint4*)W1G;
        uint4* d1 = (uint4*)smem;
#pragma unroll
        for (int k = 0; k < 4; ++k) d1[tid + k * 256] = s1[tid + k * 256];
        const uint4* s2 = (const uint4*)B2G;
        uint4* d2 = (uint4*)(smem + 16384);
#pragma unroll
        for (int k = 0; k < 2; ++k) d2[tid + k * 256] = s2[tid + k * 256];
    }
    int wv = tid >> 6, lane = tid & 63;
    int q = lane >> 4, n = lane & 15;

    int b = bi >> 9, i = bi & 511;
    size_t rowbase = (size_t)bi * 512;

    float shv = tail[n];
    float bbv = tail[8 + n];

    const float* efbase = EF + rowbase * 5;
    int pair0 = wv * 32 + n;            // col group 0; group 1 = +16

    const float* p0 = efbase + (size_t)pair0 * 5;
    float4 evA0 = *(const float4*)p0;        float evB0 = p0[4];
    float4 evA1 = *(const float4*)(p0 + 80); float evB1 = p0[84];

    __syncthreads();
    const short8* w1l = (const short8*)smem;            // [16*64] frags
    const short8* b2l = (const short8*)(smem + 16384);  // [8*64] frags

    const f32x4 z = {0.f, 0.f, 0.f, 0.f};

    for (int iter = 0; iter < 4; ++iter) {
        float4 nA0, nA1; float nB0 = 0.f, nB1 = 0.f;
        if (iter < 3) {
            const float* pn = efbase + (size_t)((iter + 1) * 128 + pair0) * 5;
            nA0 = *(const float4*)pn;        nB0 = pn[4];
            nA1 = *(const float4*)(pn + 80); nB1 = pn[84];
        }
        int jb0 = iter * 128 + wv * 32;

        short8 ef0 = make_ef8(evA0, evB0, q);
        short8 ef1 = make_ef8(evA1, evB1, q);

        f32x4 acc0 = z, acc20 = z, acc1 = z, acc21 = z;
#pragma unroll
        for (int kc = 0; kc < 8; ++kc) {
            short8 wa = w1l[2 * kc * 64 + lane];
            short8 wb = w1l[(2 * kc + 1) * 64 + lane];
            short8 b2 = b2l[kc * 64 + lane];
            f32x4 dA0 = __builtin_amdgcn_mfma_f32_16x16x32_bf16(wa, ef0, z, 0, 0, 0);
            f32x4 dB0 = __builtin_amdgcn_mfma_f32_16x16x32_bf16(wb, ef0, z, 0, 0, 0);
            f32x4 dA1 = __builtin_amdgcn_mfma_f32_16x16x32_bf16(wa, ef1, z, 0, 0, 0);
            f32x4 dB1 = __builtin_amdgcn_mfma_f32_16x16x32_bf16(wb, ef1, z, 0, 0, 0);
            uint4 av0, av1;
            av0.x = cvt_pk_bf16(fmaxf(dA0[0], 0.f), fmaxf(dA0[1], 0.f));
            av0.y = cvt_pk_bf16(fmaxf(dA0[2], 0.f), fmaxf(dA0[3], 0.f));
            av0.z = cvt_pk_bf16(fmaxf(dB0[0], 0.f), fmaxf(dB0[1], 0.f));
            av0.w = cvt_pk_bf16(fmaxf(dB0[2], 0.f), fmaxf(dB0[3], 0.f));
            av1.x = cvt_pk_bf16(fmaxf(dA1[0], 0.f), fmaxf(dA1[1], 0.f));
            av1.y = cvt_pk_bf16(fmaxf(dA1[2], 0.f), fmaxf(dA1[3], 0.f));
            av1.z = cvt_pk_bf16(fmaxf(dB1[0], 0.f), fmaxf(dB1[1], 0.f));
            av1.w = cvt_pk_bf16(fmaxf(dB1[2], 0.f), fmaxf(dB1[3], 0.f));
            short8 a0, a1;
            __builtin_memcpy(&a0, &av0, 16);
            __builtin_memcpy(&a1, &av1, 16);
            acc0  = __builtin_amdgcn_mfma_f32_16x16x32_bf16(a0, b2, acc0, 0, 0, 0);
            acc20 = __builtin_amdgcn_mfma_f32_16x16x32_bf16(a0, a0, acc20, 0, 0, 0);
            acc1  = __builtin_amdgcn_mfma_f32_16x16x32_bf16(a1, b2, acc1, 0, 0, 0);
            acc21 = __builtin_amdgcn_mfma_f32_16x16x32_bf16(a1, a1, acc21, 0, 0, 0);
        }

        ln_store(acc0, acc20, shv, bbv, lane, n, q, E2, b, i, jb0);
        ln_store(acc1, acc21, shv, bbv, lane, n, q, E2, b, i, jb0 + 16);

        evA0 = nA0; evB0 = nB0;
        evA1 = nA1; evB1 = nB1;
    }
}

// ---------------------------------------------------------------------------
// fused_qkv_edge: blocks 0..383 = QKV gemms (independent MFMA-heavy work),
// blocks 384..2431 = edge rows. launch_bounds(256,4): cap 128 VGPR.
// ---------------------------------------------------------------------------
__global__ __launch_bounds__(256, 4) void fused_qkv_edge(
    const float* __restrict__ query, const float* __restrict__ key,
    const float* __restrict__ value,
    const ushort* __restrict__ WThi, const ushort* __restrict__ WTlo,
    const float* __restrict__ bq, const float* __restrict__ bk,
    const float* __restrict__ bv,
    float* __restrict__ Qw, float* __restrict__ Ktw, float* __restrict__ Vw,
    const float* __restrict__ EF, const ushort* __restrict__ W1G,
    const ushort* __restrict__ B2G, const float* __restrict__ tail,
    ushort* __restrict__ E2)
{
    __shared__ __align__(16) char smem[24576];  // union: gemm 10240 / edge 24576
    int bid = blockIdx.x;
    if (bid < 384) {
        int z = bid >> 7, rem = bid & 127;
        int bx = rem & 31, by = rem >> 5;
        if (z == 0)
            gemm_body(query, WThi + 0 * 65536, WTlo + 0 * 65536, bq, Qw, nullptr, bx, by, smem);
        else if (z == 1)
            gemm_body(key,   WThi + 1 * 65536, WTlo + 1 * 65536, bk, nullptr, Ktw, bx, by, smem);
        else
            gemm_body(value, WThi + 2 * 65536, WTlo + 2 * 65536, bv, Vw, nullptr, bx, by, smem);
    } else {
        edge_body(EF, W1G, B2G, tail, E2, bid - 384, smem);
    }
}

// ---------------------------------------------------------------------------
// gemm_out: output projection, BM=32 -> grid MUST be (64, 4) = 256 blocks.
// ---------------------------------------------------------------------------
__global__ __launch_bounds__(256) void gemm_out(
    const float* __restrict__ A, const ushort* __restrict__ BH,
    const ushort* __restrict__ BL, const float* __restrict__ bias,
    float* __restrict__ C)
{
    __shared__ __align__(16) char smem[5120];
    gemm_body32(A, BH, BL, bias, C, blockIdx.x, blockIdx.y, smem);
}

// ---------------------------------------------------------------------------
// attn (R1/R2-proven version, unchanged): single-buffer staged K/V with
// register staging, pbuf for the P transpose, 2 barriers per chunk.
// Best-measured attn across 12 rounds (<=49.9 us, no spills).
// pbuf is the deliberate cross-phase spill target for s[][] — do NOT
// replace it with registers/shuffle (R8: +35 MB scratch) or delete the
// staging (R3: +200 MB scratch).
// ---------------------------------------------------------------------------
__global__ __launch_bounds__(256, 4) void attn_kernel(
    const float* __restrict__ Q, const float* __restrict__ Kt,
    const float* __restrict__ V, const ushort* __restrict__ E2,
    const int* __restrict__ MSK, float* __restrict__ Y)
{
    __shared__ float stage[4096];         // 16 KB: K chunk [32][128] / V chunk [128][32]
    __shared__ ushort pbuf[4][512][4];    // 16 KB: [wave][j][row] bf16

    int bh = blockIdx.x;
    int b = bh >> 3, h = bh & 7;
    int tid = threadIdx.x;
    int wv = tid >> 6, lane = tid & 63;
    int i0 = blockIdx.y * 16;
    int i = i0 + wv * 4;

    const float* Ktb = Kt + (size_t)bh * (HD * L_SEQ);
    const float* Vb  = V + (size_t)b * L_SEQ * D_EMB + h * HD;

    int wvu = __builtin_amdgcn_readfirstlane(wv);
    const float* Qs = Q + ((size_t)(b * L_SEQ + i0 + wvu * 4)) * 256 + h * HD;

    size_t erow = ((size_t)bh * L_SEQ + i) * L_SEQ;
    size_t mrow = ((size_t)b * L_SEQ + i) * L_SEQ;

    unsigned int e2p[4][4];
    int2 mkp[4][4];
#pragma unroll
    for (int r = 0; r < 4; ++r)
#pragma unroll
        for (int c = 0; c < 4; ++c) {
            int j = c * 128 + 2 * lane;
            e2p[r][c] = *(const unsigned int*)(E2 + erow + (size_t)r * L_SEQ + j);
            mkp[r][c] = *(const int2*)(MSK + mrow + (size_t)r * L_SEQ + j);
        }

    float s[4][8];
#pragma unroll
    for (int r = 0; r < 4; ++r)
#pragma unroll
        for (int t = 0; t < 8; ++t) s[r][t] = 0.f;

    for (int c = 0; c < 4; ++c) {
        if (c) __syncthreads();
        {
            int d0 = tid >> 5, jj = (tid & 31) * 4;
#pragma unroll
            for (int p = 0; p < 4; ++p) {
                int d = p * 8 + d0;
                float4 kv = *(const float4*)(Ktb + (size_t)d * L_SEQ + c * 128 + jj);
                *(float4*)&stage[d * 128 + jj] = kv;
            }
        }
        __syncthreads();
        int c2 = c * 2;
#pragma unroll
        for (int d = 0; d < HD; ++d) {
            float q0 = Qs[0 * 256 + d];
            float q1 = Qs[1 * 256 + d];
            float q2 = Qs[2 * 256 + d];
            float q3 = Qs[3 * 256 + d];
            float2 kv = *(const float2*)&stage[d * 128 + 2 * lane];
            s[0][c2]     = fmaf(q0, kv.x, s[0][c2]);
            s[0][c2 + 1] = fmaf(q0, kv.y, s[0][c2 + 1]);
            s[1][c2]     = fmaf(q1, kv.x, s[1][c2]);
            s[1][c2 + 1] = fmaf(q1, kv.y, s[1][c2 + 1]);
            s[2][c2]     = fmaf(q2, kv.x, s[2][c2]);
            s[2][c2 + 1] = fmaf(q2, kv.y, s[2][c2 + 1]);
            s[3][c2]     = fmaf(q3, kv.x, s[3][c2]);
            s[3][c2 + 1] = fmaf(q3, kv.y, s[3][c2 + 1]);
        }
    }

    const float scl = 0.17677669529663687f;  // 1/sqrt(32)
#pragma unroll
    for (int r = 0; r < 4; ++r) {
        float m = -3.0e38f;
#pragma unroll
        for (int idx = 0; idx < 8; ++idx) {
            int c = idx >> 1, u = idx & 1;
            unsigned int pk = e2p[r][c];
            float e = bf2f((ushort)(u ? (pk >> 16) : (pk & 0xffff)));
            int mk = u ? mkp[r][c].y : mkp[r][c].x;
            float v = (mk != 0) ? fmaf(s[r][idx], scl, e) : -1e30f;
            s[r][idx] = v;
            m = fmaxf(m, v);
        }
#pragma unroll
        for (int o = 32; o > 0; o >>= 1) m = fmaxf(m, __shfl_xor(m, o));
        float ssum = 0.f;
#pragma unroll
        for (int idx = 0; idx < 8; ++idx) {
            float p = __expf(s[r][idx] - m);
            s[r][idx] = p;
            ssum += p;
        }
#pragma unroll
        for (int o = 32; o > 0; o >>= 1) ssum += __shfl_xor(ssum, o);
        float inv = 1.0f / ssum;
#pragma unroll
        for (int idx = 0; idx < 8; ++idx) s[r][idx] *= inv;
    }
#pragma unroll
    for (int c = 0; c < 4; ++c) {
        int c2 = c * 2;
        uint4 w;
        w.x = cvt_pk_bf16(s[0][c2],     s[1][c2]);
        w.y = cvt_pk_bf16(s[2][c2],     s[3][c2]);
        w.z = cvt_pk_bf16(s[0][c2 + 1], s[1][c2 + 1]);
        w.w = cvt_pk_bf16(s[2][c2 + 1], s[3][c2 + 1]);
        *(uint4*)&pbuf[wv][c * 128 + 2 * lane][0] = w;
    }

    int dg = lane >> 3, js = lane & 7;
    float4 acc[4];
#pragma unroll
    for (int r = 0; r < 4; ++r) { acc[r].x = 0.f; acc[r].y = 0.f; acc[r].z = 0.f; acc[r].w = 0.f; }

    for (int c = 0; c < 4; ++c) {
        __syncthreads();
        {
            int j0 = tid >> 3, dd = (tid & 7) * 4;
#pragma unroll
            for (int p = 0; p < 4; ++p) {
                int j = p * 32 + j0;
                float4 vv = *(const float4*)(Vb + (size_t)(c * 128 + j) * D_EMB + dd);
                *(float4*)&stage[j * 32 + dd] = vv;
            }
        }
        __syncthreads();
#pragma unroll
        for (int jb = 0; jb < 16; ++jb) {
            int jj = jb * 8 + js;
            float4 v4 = *(const float4*)&stage[jj * 32 + dg * 4];
            uint2 pu = *(const uint2*)&pbuf[wv][c * 128 + jj][0];
            float p0 = asf(pu.x << 16);
            float p1 = asf(pu.x & 0xffff0000u);
            float p2 = asf(pu.y << 16);
            float p3 = asf(pu.y & 0xffff0000u);
            acc[0].x = fmaf(p0, v4.x, acc[0].x);
            acc[0].y = fmaf(p0, v4.y, acc[0].y);
            acc[0].z = fmaf(p0, v4.z, acc[0].z);
            acc[0].w = fmaf(p0, v4.w, acc[0].w);
            acc[1].x = fmaf(p1, v4.x, acc[1].x);
            acc[1].y = fmaf(p1, v4.y, acc[1].y);
            acc[1].z = fmaf(p1, v4.z, acc[1].z);
            acc[1].w = fmaf(p1, v4.w, acc[1].w);
            acc[2].x = fmaf(p2, v4.x, acc[2].x);
            acc[2].y = fmaf(p2, v4.y, acc[2].y);
            acc[2].z = fmaf(p2, v4.z, acc[2].z);
            acc[2].w = fmaf(p2, v4.w, acc[2].w);
            acc[3].x = fmaf(p3, v4.x, acc[3].x);
            acc[3].y = fmaf(p3, v4.y, acc[3].y);
            acc[3].z = fmaf(p3, v4.z, acc[3].z);
            acc[3].w = fmaf(p3, v4.w, acc[3].w);
        }
    }

#pragma unroll
    for (int off = 1; off < 8; off <<= 1) {
#pragma unroll
        for (int r = 0; r < 4; ++r) {
            acc[r].x += __shfl_xor(acc[r].x, off);
            acc[r].y += __shfl_xor(acc[r].y, off);
            acc[r].z += __shfl_xor(acc[r].z, off);
            acc[r].w += __shfl_xor(acc[r].w, off);
        }
    }
    if (js == 0) {
#pragma unroll
        for (int r = 0; r < 4; ++r)
            *(float4*)(Y + ((size_t)(b * L_SEQ + i + r)) * 256 + h * HD + dg * 4) = acc[r];
    }
}

// ---------------------------------------------------------------------------
extern "C" void kernel_launch(void* const* d_in, const int* in_sizes, int n_in,
                              void* d_out, int out_size, void* d_ws, size_t ws_size,
                              hipStream_t stream)
{
    const float* key   = (const float*)d_in[0];
    const float* value = (const float*)d_in[1];
    const float* query = (const float*)d_in[2];
    const int*   msk   = (const int*)d_in[3];
    const float* ef    = (const float*)d_in[4];
    const float* Wk  = (const float*)d_in[5];  const float* bk  = (const float*)d_in[6];
    const float* Wq  = (const float*)d_in[7];  const float* bq  = (const float*)d_in[8];
    const float* Wv  = (const float*)d_in[9];  const float* bv  = (const float*)d_in[10];
    const float* Wp  = (const float*)d_in[11]; const float* bp  = (const float*)d_in[12];
    const float* We1 = (const float*)d_in[13]; const float* be1 = (const float*)d_in[14];
    const float* lng = (const float*)d_in[15]; const float* lnb = (const float*)d_in[16];
    const float* We2 = (const float*)d_in[17]; const float* be2 = (const float*)d_in[18];

    const int MTOK = 4 * L_SEQ;          // 2048 rows
    const int NELT = MTOK * D_EMB;       // 524288

    float* ws    = (float*)d_ws;
    float* Qw    = ws;
    float* Vw    = Qw + NELT;
    float* Yw    = Vw + NELT;
    float* Ktw   = Yw + NELT;
    ushort* W1G  = (ushort*)(Ktw + NELT);   // 8192 bf16
    ushort* B2G  = W1G + 8192;              // 4096 bf16
    float* tail  = (float*)(B2G + 4096);    // 32 floats
    ushort* WThi = (ushort*)(tail + 32);    // 4*65536 bf16 (512 KB)
    ushort* WTlo = WThi + 4 * 65536;        // 4*65536 bf16 (512 KB)
    ushort* E2   = WTlo + 4 * 65536;        // 8388608 bf16 (~16.8 MB)

    hipLaunchKernelGGL(prep_kernel, dim3(259), dim3(256), 0, stream,
                       We1, be1, lng, lnb, We2, be2,
                       Wq, Wk, Wv, Wp,
                       W1G, B2G, tail, WThi, WTlo);
    hipLaunchKernelGGL(fused_qkv_edge, dim3(2432), dim3(256), 0, stream,
                       query, key, value, WThi, WTlo, bq, bk, bv,
                       Qw, Ktw, Vw,
                       ef, W1G, B2G, tail, E2);
    hipLaunchKernelGGL(attn_kernel, dim3(32, 32), dim3(256), 0, stream,
                       Qw, Ktw, Vw, E2, msk, Yw);
    hipLaunchKernelGGL(gemm_out, dim3(64, 4), dim3(256), 0, stream,
                       Yw, WThi + 3 * 65536, WTlo + 3 * 65536, bp, (float*)d_out);
}